// Round 8
// baseline (3459.302 us; speedup 1.0000x reference)
//
#include <hip/hip_runtime.h>
#include <hip/hip_bf16.h>
#include <cstdint>

#define HD 768
#define VOC 21128
#define VOCP 21248
#define NSTEPS 511
#define MROWS 4088      // 511*8
#define MPAD 4096
#define NBL 192         // lstm blocks (co-resident, 192 < 256 CUs)

typedef float f32x4 __attribute__((ext_vector_type(4)));
typedef short short8 __attribute__((ext_vector_type(8)));

// ---- workspace layout (bytes) ----
// 0        : (unused)                                                (768)
// 768      : hw8[2][3072] u64  [tag16|fp16 h_even|fp16 h_odd|tag16]  (49152)
// 49920    : Hall[4088][768] f32                                     (12558336)
// 12632576 : WdT[768][768] f32                                       (2359296)
// 14991872 : T[4096][768] bf16                                       (6291456)
// 21283328 : WvB[21248][768] bf16                                    (32636928) -> end 53920256
#define OFF_HW   768
#define OFF_HALL 49920
#define OFF_WDT  12632576ULL
#define OFF_T    14991872ULL
#define OFF_WV   21283328ULL
#define PADH 772        // h_lds row stride (bank-conflict pad)

__device__ __forceinline__ unsigned short f2bf(float x) {
  unsigned u = __float_as_uint(x);
  u += 0x7FFFu + ((u >> 16) & 1u);   // RNE
  return (unsigned short)(u >> 16);
}

__device__ __forceinline__ void gl_lds16(const void* g, void* l) {
  __builtin_amdgcn_global_load_lds(
      (const __attribute__((address_space(1))) void*)g,
      (__attribute__((address_space(3))) void*)l, 16, 0, 0);
}

// relaxed agent-scope (sc1): coherent-point traffic, no cache-wide ops
__device__ __forceinline__ void st_u64(uint64_t* p, uint64_t v) {
  __hip_atomic_store(p, v, __ATOMIC_RELAXED, __HIP_MEMORY_SCOPE_AGENT);
}
__device__ __forceinline__ uint64_t ld_u64(const uint64_t* p) {
  return __hip_atomic_load(p, __ATOMIC_RELAXED, __HIP_MEMORY_SCOPE_AGENT);
}

// wave-local xor-swizzles (within 32-lane halves; BitMode patterns)
__device__ __forceinline__ float swz8(float x) {
  return __int_as_float(__builtin_amdgcn_ds_swizzle(__float_as_int(x), 0x201F));
}
__device__ __forceinline__ float swz16(float x) {
  return __int_as_float(__builtin_amdgcn_ds_swizzle(__float_as_int(x), 0x401F));
}

// overflow-safe fast activations (rcp(inf)=0 gives exact saturation)
__device__ __forceinline__ float sigf(float x) {
  return __builtin_amdgcn_rcpf(1.f + __expf(-x));
}
__device__ __forceinline__ float tanhf_fast(float x) {
  float ax = fabsf(x);
  float e = __expf(-2.f * ax);                       // in (0,1], no overflow
  float t = (1.f - e) * __builtin_amdgcn_rcpf(1.f + e);
  return copysignf(t, x);
}

// ---------------- prep: WdT transpose, Wv->bf16 (padded), hw zero ---------
__global__ __launch_bounds__(256) void prep_kernel(
    const float* __restrict__ Wd, float* __restrict__ WdT,
    const float* __restrict__ Wv, unsigned short* __restrict__ WvB,
    uint64_t* __restrict__ hw8) {
  unsigned idx = blockIdx.x * 256 + threadIdx.x;
  unsigned stride = gridDim.x * 256;
  for (unsigned i = idx; i < 6144; i += stride) hw8[i] = 0;   // stale-tag kill
  for (unsigned i = idx; i < HD * HD; i += stride) {
    unsigned k = i / HD, j = i - k * HD;
    WdT[i] = Wd[j * HD + k];           // WdT[k][j] = Wd[j][k]
  }
  const unsigned NV = (unsigned)VOCP * HD, NVr = (unsigned)VOC * HD;
  for (unsigned i = idx; i < NV; i += stride)
    WvB[i] = f2bf(i < NVr ? Wv[i] : 0.f);
}

// ------ lstm: persistent, 192 blocks, self-validating 8B-word protocol ----
__global__ __launch_bounds__(256) void lstm_kernel(
    const float* __restrict__ cls, const float* __restrict__ Wih,
    const float* __restrict__ Whh, const float* __restrict__ bih,
    const float* __restrict__ bhh, uint64_t* __restrict__ hw8,
    float* __restrict__ Hall) {
  __shared__ float h_lds[8 * PADH];       // current h (or cls), [b][u] padded
  __shared__ float red[4][2][16][8];      // [wave][half][row][b] partials
  __shared__ float sbias[16];             // combined gate biases, local rows
  const int t = threadIdx.x;
  const int blk = blockIdx.x;
  const int p_ = t & 7;                // row-pair 0..7 (16 rows/block)
  const int s_ = t >> 3;               // k-slice 0..31 (24 k each)
  const int ks = s_ * 24;
  const int r0 = 2 * p_, r1 = r0 + 1;  // local rows; gate=r>>2, unit=r&3
  const int grow0 = (r0 >> 2) * HD + blk * 4 + (r0 & 3);
  const int grow1 = (r1 >> 2) * HD + blk * 4 + (r1 & 3);
  float w0[24], w1[24];
#pragma unroll
  for (int j = 0; j < 24; ++j) {
    w0[j] = Wih[(size_t)grow0 * HD + ks + j];
    w1[j] = Wih[(size_t)grow1 * HD + ks + j];
  }
  if (t < 16) {
    int gr = (t >> 2) * HD + blk * 4 + (t & 3);
    sbias[t] = bih[gr] + bhh[gr];
  }
  float cstate = 0.f;
  const int lane = t & 63, wv = t >> 6, hf = (lane >> 5);

  // one LSTM cell step; publishes packed [tag|h_even|h_odd|tag] u64 words
  auto do_step = [&](uint64_t* __restrict__ hw_out, int tag,
                     float* __restrict__ hall_row) {
    float acc0[8], acc1[8];
#pragma unroll
    for (int b = 0; b < 8; ++b) { acc0[b] = 0.f; acc1[b] = 0.f; }
#pragma unroll
    for (int b = 0; b < 8; ++b) {
      const float* hb = &h_lds[b * PADH + ks];
#pragma unroll
      for (int j4 = 0; j4 < 6; ++j4) {
        f32x4 hv = *reinterpret_cast<const f32x4*>(hb + j4 * 4);
#pragma unroll
        for (int e = 0; e < 4; ++e) {
          acc0[b] = fmaf(w0[j4 * 4 + e], hv[e], acc0[b]);
          acc1[b] = fmaf(w1[j4 * 4 + e], hv[e], acc1[b]);
        }
      }
    }
    // reduce over the wave's 8 k-slices: 2 swizzle rounds -> per-half sums
#pragma unroll
    for (int b = 0; b < 8; ++b) {
      acc0[b] += swz8(acc0[b]);  acc0[b] += swz16(acc0[b]);
      acc1[b] += swz8(acc1[b]);  acc1[b] += swz16(acc1[b]);
    }
    if ((lane & 31) < 8) {
#pragma unroll
      for (int b = 0; b < 8; ++b) {
        red[wv][hf][r0][b] = acc0[b];
        red[wv][hf][r1][b] = acc1[b];
      }
    }
    __syncthreads();                      // red complete
    if (t < 32) {
      int ul = t >> 3, b = t & 7;
      float gs[4];
#pragma unroll
      for (int g = 0; g < 4; ++g) {
        int r = g * 4 + ul;
        float s = sbias[r];
#pragma unroll
        for (int w2 = 0; w2 < 4; ++w2) s += red[w2][0][r][b] + red[w2][1][r][b];
        gs[g] = s;
      }
      float iv = sigf(gs[0]);
      float fv = sigf(gs[1]);
      float gv = tanhf_fast(gs[2]);
      float ov = sigf(gs[3]);
      cstate = fv * cstate + iv * gv;
      float hn = ov * tanhf_fast(cstate);
      // pair batches (b, b+1) in-wave; even-b lanes store one 8B atomic word
      float hp = __shfl_down(hn, 1);
      union { _Float16 f; unsigned short u; } c0, c1;
      c0.f = (_Float16)hn;
      c1.f = (_Float16)hp;
      if ((b & 1) == 0) {
        uint64_t wd = (uint64_t)(uint16_t)tag
                    | ((uint64_t)c0.u << 16)
                    | ((uint64_t)c1.u << 32)
                    | ((uint64_t)(uint16_t)tag << 48);
        st_u64(&hw_out[(blk * 4 + ul) * 4 + (b >> 1)], wd);
      }
      if (hall_row) hall_row[(size_t)b * HD + blk * 4 + ul] = hn;  // plain f32
    }
  };

  // pre-step: h1 = cell(cls, 0, 0) -> gates = cls@Wih^T + (bih+bhh)
  for (int i = t; i < 1536; i += 256) {
    int b = i / 192, c4 = i - b * 192;
    *reinterpret_cast<f32x4*>(&h_lds[b * PADH + c4 * 4]) =
        reinterpret_cast<const f32x4*>(cls)[i];
  }
  __syncthreads();
  do_step(hw8 + 3072, 1, nullptr);       // h_1 -> parity 1, tag 1
  // switch to combined weights W_ih + W_hh (inside the scan, x == h)
#pragma unroll
  for (int j = 0; j < 24; ++j) {
    w0[j] += Whh[(size_t)grow0 * HD + ks + j];
    w1[j] += Whh[(size_t)grow1 * HD + ks + j];
  }
  for (int s = 1; s <= NSTEPS; ++s) {
    // poll own 12 u64 words of h_s; word g: unit=g>>2, batches 2(g&3),+1.
    // Validated words decode to LDS immediately; only missing re-polled.
    {
      const uint64_t* src = hw8 + (s & 1) * 3072;
      const uint32_t tg = (uint32_t)s;
      uint32_t pend = 0xFFFu;
      while (pend) {
        uint32_t np = 0;
#pragma unroll
        for (int k = 0; k < 12; ++k) {
          if (pend & (1u << k)) {
            int g = t + (k << 8);
            uint64_t v = ld_u64(&src[g]);
            if ((uint32_t)(v & 0xFFFFu) == tg && (uint32_t)(v >> 48) == tg) {
              int u = g >> 2, b0 = (g & 3) * 2;
              union { unsigned short u16; _Float16 f16; } d0, d1;
              d0.u16 = (unsigned short)((v >> 16) & 0xFFFFu);
              d1.u16 = (unsigned short)((v >> 32) & 0xFFFFu);
              h_lds[b0 * PADH + u] = (float)d0.f16;
              h_lds[(b0 + 1) * PADH + u] = (float)d1.f16;
            } else {
              np |= (1u << k);
            }
          }
        }
        pend = np;
      }
    }
    __syncthreads();                     // h_s staged in LDS
    do_step(hw8 + ((s + 1) & 1) * 3072, s + 1,
            Hall + (size_t)(s - 1) * (8 * HD));
  }
}

// ---------------- head: dense + gelu(erf) + LayerNorm -> T (bf16) ----------
__global__ __launch_bounds__(256) void head_kernel(
    const float* __restrict__ Hall, const float* __restrict__ WdT,
    const float* __restrict__ bd, const float* __restrict__ gamma,
    const float* __restrict__ beta, unsigned short* __restrict__ Tm) {
  __shared__ float hT[HD][16];
  __shared__ float rbuf[4][16];
  __shared__ float mu_s[16], rs_s[16];
  const int t = threadIdx.x;
  const int r0 = blockIdx.x * 16;
  {
    const int row = t & 15, ksl = t >> 4;
    const float* src = Hall + (size_t)(r0 + row) * HD + ksl * 48;
#pragma unroll
    for (int i = 0; i < 12; ++i) {
      f32x4 v = *reinterpret_cast<const f32x4*>(src + i * 4);
      int k = ksl * 48 + i * 4;
      hT[k][row] = v[0]; hT[k + 1][row] = v[1];
      hT[k + 2][row] = v[2]; hT[k + 3][row] = v[3];
    }
  }
  __syncthreads();
  float a0[16], a1[16], a2[16];
#pragma unroll
  for (int r = 0; r < 16; ++r) { a0[r] = 0.f; a1[r] = 0.f; a2[r] = 0.f; }
  for (int k = 0; k < HD; ++k) {
    float wa = WdT[(size_t)k * HD + t];
    float wb = WdT[(size_t)k * HD + t + 256];
    float wc = WdT[(size_t)k * HD + t + 512];
    f32x4 hv4[4];
#pragma unroll
    for (int q = 0; q < 4; ++q)
      hv4[q] = *reinterpret_cast<const f32x4*>(&hT[k][q * 4]);
#pragma unroll
    for (int r = 0; r < 16; ++r) {
      float hv = hv4[r >> 2][r & 3];
      a0[r] = fmaf(wa, hv, a0[r]);
      a1[r] = fmaf(wb, hv, a1[r]);
      a2[r] = fmaf(wc, hv, a2[r]);
    }
  }
  float g0 = gamma[t], g1 = gamma[t + 256], g2 = gamma[t + 512];
  float be0 = beta[t], be1 = beta[t + 256], be2 = beta[t + 512];
  float bd0 = bd[t], bd1 = bd[t + 256], bd2 = bd[t + 512];
#pragma unroll
  for (int r = 0; r < 16; ++r) {
    float x;
    x = a0[r] + bd0; a0[r] = 0.5f * x * (1.f + erff(x * 0.7071067811865476f));
    x = a1[r] + bd1; a1[r] = 0.5f * x * (1.f + erff(x * 0.7071067811865476f));
    x = a2[r] + bd2; a2[r] = 0.5f * x * (1.f + erff(x * 0.7071067811865476f));
  }
  float ps[16];
  const int lane = t & 63, wv = t >> 6;
#pragma unroll
  for (int r = 0; r < 16; ++r) ps[r] = a0[r] + a1[r] + a2[r];
#pragma unroll
  for (int r = 0; r < 16; ++r)
#pragma unroll
    for (int m = 1; m < 64; m <<= 1) ps[r] += __shfl_xor(ps[r], m);
  if (lane == 0) {
#pragma unroll
    for (int r = 0; r < 16; ++r) rbuf[wv][r] = ps[r];
  }
  __syncthreads();
  if (t < 16) mu_s[t] = (rbuf[0][t] + rbuf[1][t] + rbuf[2][t] + rbuf[3][t]) * (1.f / HD);
  __syncthreads();
#pragma unroll
  for (int r = 0; r < 16; ++r) {
    float mu = mu_s[r];
    float d0 = a0[r] - mu, d1 = a1[r] - mu, d2 = a2[r] - mu;
    ps[r] = d0 * d0 + d1 * d1 + d2 * d2;
  }
#pragma unroll
  for (int r = 0; r < 16; ++r)
#pragma unroll
    for (int m = 1; m < 64; m <<= 1) ps[r] += __shfl_xor(ps[r], m);
  if (lane == 0) {
#pragma unroll
    for (int r = 0; r < 16; ++r) rbuf[wv][r] = ps[r];
  }
  __syncthreads();
  if (t < 16)
    rs_s[t] = 1.f / sqrtf((rbuf[0][t] + rbuf[1][t] + rbuf[2][t] + rbuf[3][t]) * (1.f / HD) + 1e-12f);
  __syncthreads();
#pragma unroll
  for (int r = 0; r < 16; ++r) {
    float mu = mu_s[r], rs = rs_s[r];
    size_t ro = (size_t)(r0 + r) * HD;
    Tm[ro + t]       = f2bf((a0[r] - mu) * rs * g0 + be0);
    Tm[ro + t + 256] = f2bf((a1[r] - mu) * rs * g1 + be1);
    Tm[ro + t + 512] = f2bf((a2[r] - mu) * rs * g2 + be2);
  }
}

// ---------------- decoder GEMM: out = T @ WvB^T + bvoc  (bf16 MFMA) -------
__global__ __launch_bounds__(256) void gemm_kernel(
    const unsigned short* __restrict__ Tm, const unsigned short* __restrict__ Wv,
    const float* __restrict__ bvoc, float* __restrict__ out) {
  __shared__ unsigned short As[128 * 64];
  __shared__ unsigned short Bs[128 * 64];
  const int t = threadIdx.x;
  const int lane = t & 63, wid = t >> 6;
  const int wm = wid >> 1, wn = wid & 1;
  const int m0 = blockIdx.y * 128, n0 = blockIdx.x * 128;
  const int lrow = lane & 15, lgrp = lane >> 4;
  f32x4 acc[4][4] = {};
  for (int kt = 0; kt < HD; kt += 64) {
#pragma unroll
    for (int it = 0; it < 4; ++it) {
      int slot = it * 256 + t;
      int row = slot >> 3, g = slot & 7;
      int sg = g ^ (row & 7);                       // pre-swizzled source
      const unsigned short* sa = Tm + (size_t)(m0 + row) * HD + kt + sg * 8;
      const unsigned short* sb = Wv + (size_t)(n0 + row) * HD + kt + sg * 8;
      unsigned short* da = &As[(it * 256 + wid * 64) * 8];  // wave-uniform base
      unsigned short* db = &Bs[(it * 256 + wid * 64) * 8];
      gl_lds16(sa, da);
      gl_lds16(sb, db);
    }
    __syncthreads();
#pragma unroll
    for (int kk = 0; kk < 2; ++kk) {
      short8 af[4], bfr[4];
#pragma unroll
      for (int i = 0; i < 4; ++i) {
        int row = wm * 64 + i * 16 + lrow;
        int gg = (kk * 4 + lgrp) ^ (row & 7);       // swizzled read
        af[i] = *reinterpret_cast<const short8*>(&As[row * 64 + gg * 8]);
      }
#pragma unroll
      for (int j = 0; j < 4; ++j) {
        int row = wn * 64 + j * 16 + lrow;
        int gg = (kk * 4 + lgrp) ^ (row & 7);
        bfr[j] = *reinterpret_cast<const short8*>(&Bs[row * 64 + gg * 8]);
      }
#pragma unroll
      for (int i = 0; i < 4; ++i)
#pragma unroll
        for (int j = 0; j < 4; ++j)
          acc[i][j] = __builtin_amdgcn_mfma_f32_16x16x32_bf16(af[i], bfr[j], acc[i][j], 0, 0, 0);
    }
    __syncthreads();
  }
#pragma unroll
  for (int j = 0; j < 4; ++j) {
    int col = n0 + wn * 64 + j * 16 + lrow;
    bool cok = col < VOC;
    float bv = cok ? bvoc[col] : 0.f;
#pragma unroll
    for (int i = 0; i < 4; ++i) {
      int rbase = m0 + wm * 64 + i * 16 + lgrp * 4;
#pragma unroll
      for (int e = 0; e < 4; ++e) {
        int row = rbase + e;
        if (cok && row < MROWS) out[(size_t)row * VOC + col] = acc[i][j][e] + bv;
      }
    }
  }
}

extern "C" void kernel_launch(void* const* d_in, const int* in_sizes, int n_in,
                              void* d_out, int out_size, void* d_ws, size_t ws_size,
                              hipStream_t stream) {
  (void)in_sizes; (void)n_in; (void)out_size; (void)ws_size;
  const float* cls  = (const float*)d_in[0];
  const float* Wih  = (const float*)d_in[1];
  const float* Whh  = (const float*)d_in[2];
  const float* bih  = (const float*)d_in[3];
  const float* bhh  = (const float*)d_in[4];
  const float* Wd   = (const float*)d_in[5];
  const float* bd   = (const float*)d_in[6];
  const float* gmm  = (const float*)d_in[7];
  const float* bet  = (const float*)d_in[8];
  const float* Wv   = (const float*)d_in[9];
  const float* bvoc = (const float*)d_in[10];
  char* ws = (char*)d_ws;
  uint64_t* hw8 = (uint64_t*)(ws + OFF_HW);
  float* Hall  = (float*)(ws + OFF_HALL);
  float* WdT   = (float*)(ws + OFF_WDT);
  unsigned short* Tm  = (unsigned short*)(ws + OFF_T);
  unsigned short* WvB = (unsigned short*)(ws + OFF_WV);
  float* out = (float*)d_out;

  hipLaunchKernelGGL(prep_kernel, dim3(4096), dim3(256), 0, stream, Wd, WdT, Wv, WvB, hw8);
  hipLaunchKernelGGL(lstm_kernel, dim3(NBL), dim3(256), 0, stream,
                     cls, Wih, Whh, bih, bhh, hw8, Hall);
  hipLaunchKernelGGL(head_kernel, dim3(MPAD / 16), dim3(256), 0, stream,
                     Hall, WdT, bd, gmm, bet, Tm);
  hipLaunchKernelGGL(gemm_kernel, dim3(VOCP / 128, MPAD / 128), dim3(256), 0, stream,
                     Tm, WvB, bvoc, out);
}

// Round 9
// 2232.487 us; speedup vs baseline: 1.5495x; 1.5495x over previous
//
#include <hip/hip_runtime.h>
#include <hip/hip_bf16.h>
#include <cstdint>

#define HD 768
#define VOC 21128
#define VOCP 21248
#define NSTEPS 511
#define MROWS 4088      // 511*8
#define MPAD 4096
#define NBL 192         // lstm blocks (co-resident, 192 < 256 CUs)

typedef float f32x4 __attribute__((ext_vector_type(4)));
typedef short short8 __attribute__((ext_vector_type(8)));

// ---- workspace layout (bytes) ----
// 0        : (unused)                                                (768)
// 768      : hw8[2][3072] u64  [tag16|fp16 h_even|fp16 h_odd|tag16]  (49152)
// 49920    : Hall[4088][768] f32                                     (12558336)
// 12632576 : WdT[768][768] f32                                       (2359296)
// 14991872 : T[4096][768] bf16                                       (6291456)
// 21283328 : WvB[21248][768] bf16                                    (32636928) -> end 53920256
#define OFF_HW   768
#define OFF_HALL 49920
#define OFF_WDT  12632576ULL
#define OFF_T    14991872ULL
#define OFF_WV   21283328ULL
#define PADH 772        // h_lds row stride (bank-conflict pad)

__device__ __forceinline__ unsigned short f2bf(float x) {
  unsigned u = __float_as_uint(x);
  u += 0x7FFFu + ((u >> 16) & 1u);   // RNE
  return (unsigned short)(u >> 16);
}

__device__ __forceinline__ void gl_lds16(const void* g, void* l) {
  __builtin_amdgcn_global_load_lds(
      (const __attribute__((address_space(1))) void*)g,
      (__attribute__((address_space(3))) void*)l, 16, 0, 0);
}

// relaxed agent-scope (sc1): coherent-point traffic, no cache-wide ops
__device__ __forceinline__ void st_u64(uint64_t* p, uint64_t v) {
  __hip_atomic_store(p, v, __ATOMIC_RELAXED, __HIP_MEMORY_SCOPE_AGENT);
}
__device__ __forceinline__ uint64_t ld_u64(const uint64_t* p) {
  return __hip_atomic_load(p, __ATOMIC_RELAXED, __HIP_MEMORY_SCOPE_AGENT);
}

// wave-local xor-swizzles (within 32-lane halves; BitMode patterns)
__device__ __forceinline__ float swz8(float x) {
  return __int_as_float(__builtin_amdgcn_ds_swizzle(__float_as_int(x), 0x201F));
}
__device__ __forceinline__ float swz16(float x) {
  return __int_as_float(__builtin_amdgcn_ds_swizzle(__float_as_int(x), 0x401F));
}

// overflow-safe fast activations (rcp(inf)=0 gives exact saturation)
__device__ __forceinline__ float sigf(float x) {
  return __builtin_amdgcn_rcpf(1.f + __expf(-x));
}
__device__ __forceinline__ float tanhf_fast(float x) {
  float ax = fabsf(x);
  float e = __expf(-2.f * ax);                       // in (0,1], no overflow
  float t = (1.f - e) * __builtin_amdgcn_rcpf(1.f + e);
  return copysignf(t, x);
}

// ---------------- prep: WdT transpose, Wv->bf16 (padded), hw zero ---------
__global__ __launch_bounds__(256) void prep_kernel(
    const float* __restrict__ Wd, float* __restrict__ WdT,
    const float* __restrict__ Wv, unsigned short* __restrict__ WvB,
    uint64_t* __restrict__ hw8) {
  unsigned idx = blockIdx.x * 256 + threadIdx.x;
  unsigned stride = gridDim.x * 256;
  for (unsigned i = idx; i < 6144; i += stride) hw8[i] = 0;   // stale-tag kill
  for (unsigned i = idx; i < HD * HD; i += stride) {
    unsigned k = i / HD, j = i - k * HD;
    WdT[i] = Wd[j * HD + k];           // WdT[k][j] = Wd[j][k]
  }
  const unsigned NV = (unsigned)VOCP * HD, NVr = (unsigned)VOC * HD;
  for (unsigned i = idx; i < NV; i += stride)
    WvB[i] = f2bf(i < NVr ? Wv[i] : 0.f);
}

// ------ lstm: persistent, 192 blocks, self-validating 8B-word protocol ----
__global__ __launch_bounds__(256) void lstm_kernel(
    const float* __restrict__ cls, const float* __restrict__ Wih,
    const float* __restrict__ Whh, const float* __restrict__ bih,
    const float* __restrict__ bhh, uint64_t* __restrict__ hw8,
    float* __restrict__ Hall) {
  __shared__ float h_lds[8 * PADH];       // current h (or cls), [b][u] padded
  __shared__ float red[4][2][16][8];      // [wave][half][row][b] partials
  __shared__ float sbias[16];             // combined gate biases, local rows
  const int t = threadIdx.x;
  const int blk = blockIdx.x;
  const int p_ = t & 7;                // row-pair 0..7 (16 rows/block)
  const int s_ = t >> 3;               // k-slice 0..31 (24 k each)
  const int ks = s_ * 24;
  const int r0 = 2 * p_, r1 = r0 + 1;  // local rows; gate=r>>2, unit=r&3
  const int grow0 = (r0 >> 2) * HD + blk * 4 + (r0 & 3);
  const int grow1 = (r1 >> 2) * HD + blk * 4 + (r1 & 3);
  float w0[24], w1[24];
#pragma unroll
  for (int j = 0; j < 24; ++j) {
    w0[j] = Wih[(size_t)grow0 * HD + ks + j];
    w1[j] = Wih[(size_t)grow1 * HD + ks + j];
  }
  if (t < 16) {
    int gr = (t >> 2) * HD + blk * 4 + (t & 3);
    sbias[t] = bih[gr] + bhh[gr];
  }
  float cstate = 0.f;
  const int lane = t & 63, wv = t >> 6, hf = (lane >> 5);

  // one LSTM cell step; publishes packed [tag|h_even|h_odd|tag] u64 words
  auto do_step = [&](uint64_t* __restrict__ hw_out, int tag,
                     float* __restrict__ hall_row) {
    float acc0[8], acc1[8];
#pragma unroll
    for (int b = 0; b < 8; ++b) { acc0[b] = 0.f; acc1[b] = 0.f; }
#pragma unroll
    for (int b = 0; b < 8; ++b) {
      const float* hb = &h_lds[b * PADH + ks];
#pragma unroll
      for (int j4 = 0; j4 < 6; ++j4) {
        f32x4 hv = *reinterpret_cast<const f32x4*>(hb + j4 * 4);
#pragma unroll
        for (int e = 0; e < 4; ++e) {
          acc0[b] = fmaf(w0[j4 * 4 + e], hv[e], acc0[b]);
          acc1[b] = fmaf(w1[j4 * 4 + e], hv[e], acc1[b]);
        }
      }
    }
    // reduce over the wave's 8 k-slices: 2 swizzle rounds -> per-half sums
#pragma unroll
    for (int b = 0; b < 8; ++b) {
      acc0[b] += swz8(acc0[b]);  acc0[b] += swz16(acc0[b]);
      acc1[b] += swz8(acc1[b]);  acc1[b] += swz16(acc1[b]);
    }
    if ((lane & 31) < 8) {
#pragma unroll
      for (int b = 0; b < 8; ++b) {
        red[wv][hf][r0][b] = acc0[b];
        red[wv][hf][r1][b] = acc1[b];
      }
    }
    __syncthreads();                      // red complete
    if (t < 32) {
      int ul = t >> 3, b = t & 7;
      float gs[4];
#pragma unroll
      for (int g = 0; g < 4; ++g) {
        int r = g * 4 + ul;
        float s = sbias[r];
#pragma unroll
        for (int w2 = 0; w2 < 4; ++w2) s += red[w2][0][r][b] + red[w2][1][r][b];
        gs[g] = s;
      }
      float iv = sigf(gs[0]);
      float fv = sigf(gs[1]);
      float gv = tanhf_fast(gs[2]);
      float ov = sigf(gs[3]);
      cstate = fv * cstate + iv * gv;
      float hn = ov * tanhf_fast(cstate);
      // pair batches (b, b+1) in-wave; even-b lanes store one 8B atomic word
      float hp = __shfl_down(hn, 1);
      union { _Float16 f; unsigned short u; } c0, c1;
      c0.f = (_Float16)hn;
      c1.f = (_Float16)hp;
      if ((b & 1) == 0) {
        uint64_t wd = (uint64_t)(uint16_t)tag
                    | ((uint64_t)c0.u << 16)
                    | ((uint64_t)c1.u << 32)
                    | ((uint64_t)(uint16_t)tag << 48);
        st_u64(&hw_out[(blk * 4 + ul) * 4 + (b >> 1)], wd);
      }
      if (hall_row) hall_row[(size_t)b * HD + blk * 4 + ul] = hn;  // plain f32
    }
  };

  // pre-step: h1 = cell(cls, 0, 0) -> gates = cls@Wih^T + (bih+bhh)
  for (int i = t; i < 1536; i += 256) {
    int b = i / 192, c4 = i - b * 192;
    *reinterpret_cast<f32x4*>(&h_lds[b * PADH + c4 * 4]) =
        reinterpret_cast<const f32x4*>(cls)[i];
  }
  __syncthreads();
  do_step(hw8 + 3072, 1, nullptr);       // h_1 -> parity 1, tag 1
  // switch to combined weights W_ih + W_hh (inside the scan, x == h)
#pragma unroll
  for (int j = 0; j < 24; ++j) {
    w0[j] += Whh[(size_t)grow0 * HD + ks + j];
    w1[j] += Whh[(size_t)grow1 * HD + ks + j];
  }
  for (int s = 1; s <= NSTEPS; ++s) {
    // poll own 12 u64 words of h_s; word g: unit=g>>2, batches 2(g&3),+1.
    // BRANCH-FREE BATCHED poll: all 12 loads issued unconditionally each
    // round (full MLP, single waitcnt), then validate; decode after loop.
    {
      const uint64_t* src = hw8 + (s & 1) * 3072;
      const uint32_t tg = (uint32_t)s;
      uint64_t w[12];
      bool ok;
      do {
        ok = true;
#pragma unroll
        for (int k = 0; k < 12; ++k) w[k] = ld_u64(&src[t + (k << 8)]);
#pragma unroll
        for (int k = 0; k < 12; ++k)
          ok &= ((uint32_t)(w[k] & 0xFFFFu) == tg) &
                ((uint32_t)(w[k] >> 48) == tg);
      } while (!ok);
#pragma unroll
      for (int k = 0; k < 12; ++k) {
        int g = t + (k << 8);
        int u = g >> 2, b0 = (g & 3) * 2;
        union { unsigned short u16; _Float16 f16; } d0, d1;
        d0.u16 = (unsigned short)((w[k] >> 16) & 0xFFFFu);
        d1.u16 = (unsigned short)((w[k] >> 32) & 0xFFFFu);
        h_lds[b0 * PADH + u] = (float)d0.f16;
        h_lds[(b0 + 1) * PADH + u] = (float)d1.f16;
      }
    }
    __syncthreads();                     // h_s staged in LDS
    do_step(hw8 + ((s + 1) & 1) * 3072, s + 1,
            Hall + (size_t)(s - 1) * (8 * HD));
  }
}

// ---------------- head: dense + gelu(erf) + LayerNorm -> T (bf16) ----------
__global__ __launch_bounds__(256) void head_kernel(
    const float* __restrict__ Hall, const float* __restrict__ WdT,
    const float* __restrict__ bd, const float* __restrict__ gamma,
    const float* __restrict__ beta, unsigned short* __restrict__ Tm) {
  __shared__ float hT[HD][16];
  __shared__ float rbuf[4][16];
  __shared__ float mu_s[16], rs_s[16];
  const int t = threadIdx.x;
  const int r0 = blockIdx.x * 16;
  {
    const int row = t & 15, ksl = t >> 4;
    const float* src = Hall + (size_t)(r0 + row) * HD + ksl * 48;
#pragma unroll
    for (int i = 0; i < 12; ++i) {
      f32x4 v = *reinterpret_cast<const f32x4*>(src + i * 4);
      int k = ksl * 48 + i * 4;
      hT[k][row] = v[0]; hT[k + 1][row] = v[1];
      hT[k + 2][row] = v[2]; hT[k + 3][row] = v[3];
    }
  }
  __syncthreads();
  float a0[16], a1[16], a2[16];
#pragma unroll
  for (int r = 0; r < 16; ++r) { a0[r] = 0.f; a1[r] = 0.f; a2[r] = 0.f; }
  for (int k = 0; k < HD; ++k) {
    float wa = WdT[(size_t)k * HD + t];
    float wb = WdT[(size_t)k * HD + t + 256];
    float wc = WdT[(size_t)k * HD + t + 512];
    f32x4 hv4[4];
#pragma unroll
    for (int q = 0; q < 4; ++q)
      hv4[q] = *reinterpret_cast<const f32x4*>(&hT[k][q * 4]);
#pragma unroll
    for (int r = 0; r < 16; ++r) {
      float hv = hv4[r >> 2][r & 3];
      a0[r] = fmaf(wa, hv, a0[r]);
      a1[r] = fmaf(wb, hv, a1[r]);
      a2[r] = fmaf(wc, hv, a2[r]);
    }
  }
  float g0 = gamma[t], g1 = gamma[t + 256], g2 = gamma[t + 512];
  float be0 = beta[t], be1 = beta[t + 256], be2 = beta[t + 512];
  float bd0 = bd[t], bd1 = bd[t + 256], bd2 = bd[t + 512];
#pragma unroll
  for (int r = 0; r < 16; ++r) {
    float x;
    x = a0[r] + bd0; a0[r] = 0.5f * x * (1.f + erff(x * 0.7071067811865476f));
    x = a1[r] + bd1; a1[r] = 0.5f * x * (1.f + erff(x * 0.7071067811865476f));
    x = a2[r] + bd2; a2[r] = 0.5f * x * (1.f + erff(x * 0.7071067811865476f));
  }
  float ps[16];
  const int lane = t & 63, wv = t >> 6;
#pragma unroll
  for (int r = 0; r < 16; ++r) ps[r] = a0[r] + a1[r] + a2[r];
#pragma unroll
  for (int r = 0; r < 16; ++r)
#pragma unroll
    for (int m = 1; m < 64; m <<= 1) ps[r] += __shfl_xor(ps[r], m);
  if (lane == 0) {
#pragma unroll
    for (int r = 0; r < 16; ++r) rbuf[wv][r] = ps[r];
  }
  __syncthreads();
  if (t < 16) mu_s[t] = (rbuf[0][t] + rbuf[1][t] + rbuf[2][t] + rbuf[3][t]) * (1.f / HD);
  __syncthreads();
#pragma unroll
  for (int r = 0; r < 16; ++r) {
    float mu = mu_s[r];
    float d0 = a0[r] - mu, d1 = a1[r] - mu, d2 = a2[r] - mu;
    ps[r] = d0 * d0 + d1 * d1 + d2 * d2;
  }
#pragma unroll
  for (int r = 0; r < 16; ++r)
#pragma unroll
    for (int m = 1; m < 64; m <<= 1) ps[r] += __shfl_xor(ps[r], m);
  if (lane == 0) {
#pragma unroll
    for (int r = 0; r < 16; ++r) rbuf[wv][r] = ps[r];
  }
  __syncthreads();
  if (t < 16)
    rs_s[t] = 1.f / sqrtf((rbuf[0][t] + rbuf[1][t] + rbuf[2][t] + rbuf[3][t]) * (1.f / HD) + 1e-12f);
  __syncthreads();
#pragma unroll
  for (int r = 0; r < 16; ++r) {
    float mu = mu_s[r], rs = rs_s[r];
    size_t ro = (size_t)(r0 + r) * HD;
    Tm[ro + t]       = f2bf((a0[r] - mu) * rs * g0 + be0);
    Tm[ro + t + 256] = f2bf((a1[r] - mu) * rs * g1 + be1);
    Tm[ro + t + 512] = f2bf((a2[r] - mu) * rs * g2 + be2);
  }
}

// ---------------- decoder GEMM: out = T @ WvB^T + bvoc  (bf16 MFMA) -------
__global__ __launch_bounds__(256) void gemm_kernel(
    const unsigned short* __restrict__ Tm, const unsigned short* __restrict__ Wv,
    const float* __restrict__ bvoc, float* __restrict__ out) {
  __shared__ unsigned short As[128 * 64];
  __shared__ unsigned short Bs[128 * 64];
  const int t = threadIdx.x;
  const int lane = t & 63, wid = t >> 6;
  const int wm = wid >> 1, wn = wid & 1;
  const int m0 = blockIdx.y * 128, n0 = blockIdx.x * 128;
  const int lrow = lane & 15, lgrp = lane >> 4;
  f32x4 acc[4][4] = {};
  for (int kt = 0; kt < HD; kt += 64) {
#pragma unroll
    for (int it = 0; it < 4; ++it) {
      int slot = it * 256 + t;
      int row = slot >> 3, g = slot & 7;
      int sg = g ^ (row & 7);                       // pre-swizzled source
      const unsigned short* sa = Tm + (size_t)(m0 + row) * HD + kt + sg * 8;
      const unsigned short* sb = Wv + (size_t)(n0 + row) * HD + kt + sg * 8;
      unsigned short* da = &As[(it * 256 + wid * 64) * 8];  // wave-uniform base
      unsigned short* db = &Bs[(it * 256 + wid * 64) * 8];
      gl_lds16(sa, da);
      gl_lds16(sb, db);
    }
    __syncthreads();
#pragma unroll
    for (int kk = 0; kk < 2; ++kk) {
      short8 af[4], bfr[4];
#pragma unroll
      for (int i = 0; i < 4; ++i) {
        int row = wm * 64 + i * 16 + lrow;
        int gg = (kk * 4 + lgrp) ^ (row & 7);       // swizzled read
        af[i] = *reinterpret_cast<const short8*>(&As[row * 64 + gg * 8]);
      }
#pragma unroll
      for (int j = 0; j < 4; ++j) {
        int row = wn * 64 + j * 16 + lrow;
        int gg = (kk * 4 + lgrp) ^ (row & 7);
        bfr[j] = *reinterpret_cast<const short8*>(&Bs[row * 64 + gg * 8]);
      }
#pragma unroll
      for (int i = 0; i < 4; ++i)
#pragma unroll
        for (int j = 0; j < 4; ++j)
          acc[i][j] = __builtin_amdgcn_mfma_f32_16x16x32_bf16(af[i], bfr[j], acc[i][j], 0, 0, 0);
    }
    __syncthreads();
  }
#pragma unroll
  for (int j = 0; j < 4; ++j) {
    int col = n0 + wn * 64 + j * 16 + lrow;
    bool cok = col < VOC;
    float bv = cok ? bvoc[col] : 0.f;
#pragma unroll
    for (int i = 0; i < 4; ++i) {
      int rbase = m0 + wm * 64 + i * 16 + lgrp * 4;
#pragma unroll
      for (int e = 0; e < 4; ++e) {
        int row = rbase + e;
        if (cok && row < MROWS) out[(size_t)row * VOC + col] = acc[i][j][e] + bv;
      }
    }
  }
}

extern "C" void kernel_launch(void* const* d_in, const int* in_sizes, int n_in,
                              void* d_out, int out_size, void* d_ws, size_t ws_size,
                              hipStream_t stream) {
  (void)in_sizes; (void)n_in; (void)out_size; (void)ws_size;
  const float* cls  = (const float*)d_in[0];
  const float* Wih  = (const float*)d_in[1];
  const float* Whh  = (const float*)d_in[2];
  const float* bih  = (const float*)d_in[3];
  const float* bhh  = (const float*)d_in[4];
  const float* Wd   = (const float*)d_in[5];
  const float* bd   = (const float*)d_in[6];
  const float* gmm  = (const float*)d_in[7];
  const float* bet  = (const float*)d_in[8];
  const float* Wv   = (const float*)d_in[9];
  const float* bvoc = (const float*)d_in[10];
  char* ws = (char*)d_ws;
  uint64_t* hw8 = (uint64_t*)(ws + OFF_HW);
  float* Hall  = (float*)(ws + OFF_HALL);
  float* WdT   = (float*)(ws + OFF_WDT);
  unsigned short* Tm  = (unsigned short*)(ws + OFF_T);
  unsigned short* WvB = (unsigned short*)(ws + OFF_WV);
  float* out = (float*)d_out;

  hipLaunchKernelGGL(prep_kernel, dim3(4096), dim3(256), 0, stream, Wd, WdT, Wv, WvB, hw8);
  hipLaunchKernelGGL(lstm_kernel, dim3(NBL), dim3(256), 0, stream,
                     cls, Wih, Whh, bih, bhh, hw8, Hall);
  hipLaunchKernelGGL(head_kernel, dim3(MPAD / 16), dim3(256), 0, stream,
                     Hall, WdT, bd, gmm, bet, Tm);
  hipLaunchKernelGGL(gemm_kernel, dim3(VOCP / 128, MPAD / 128), dim3(256), 0, stream,
                     Tm, WvB, bvoc, out);
}